// Round 1
// baseline (190.895 us; speedup 1.0000x reference)
//
#include <hip/hip_runtime.h>

// Xonv2D: per-location conv. B=32, CIN=16, H=W=64, COUT=32, K=3, pad=1.
// out[b,o,h,w] = sum_{c,kh,kw} x[b,c,h+kh-1,w+kw-1] * W[h,w,o,c,kh,kw] + bias[h,w,o]
//
// Strategy: one wave (64 thr) per location -> 32x32x144 GEMM via
// mfma_f32_16x16x32_bf16. Weights (75.5 MB, the big stream) are read
// DIRECTLY from global into B-fragments (contiguous in [o][p] layout),
// no LDS staging. x patches go through LDS [b][160] bf16 so A-frags are
// contiguous b128 reads. XCD swizzle: h-rows grouped per XCD, w fastest,
// for output write-combining in L2.

#define BB    32
#define CIN   16
#define HH    64
#define WW    64
#define COUT  32
#define PP    144   // CIN*3*3
#define PPAD  160   // 5 chunks of K=32

typedef float v4f  __attribute__((ext_vector_type(4)));
typedef short v8s  __attribute__((ext_vector_type(8)));

__device__ __forceinline__ unsigned short f2bf(float f) {
    unsigned int u = __builtin_bit_cast(unsigned int, f);
    u += 0x7fffu + ((u >> 16) & 1u);          // RNE
    return (unsigned short)(u >> 16);
}
__device__ __forceinline__ unsigned int pk2(float a, float b) {
    return (unsigned int)f2bf(a) | ((unsigned int)f2bf(b) << 16);
}

union U16 { uint4 u; v8s s; };

__global__ __launch_bounds__(64) void xonv_kernel(
    const float* __restrict__ x,
    const float* __restrict__ weights,
    const float* __restrict__ bias,
    float* __restrict__ out)
{
    const int l = threadIdx.x;            // 0..63
    const int bi = blockIdx.x;            // 0..4095

    // XCD-aware swizzle: xcd = bi & 7 owns h in [xcd*8, xcd*8+8), w fastest.
    const int xcd = bi & 7;
    const int t   = bi >> 3;              // 0..511
    const int h   = xcd * 8 + (t >> 6);   // 0..63
    const int w   = t & 63;               // 0..63

    __shared__ unsigned short Abf[BB][PPAD];   // x patches, bf16, [b][p]

    // ---------------- stage A (x patches) ----------------
    // lane: b = l&31, half = l>>5 covers p in [half*72, half*72+72)
    {
        const int b    = l & 31;
        const int half = l >> 5;
        const float* xb = x + ((size_t)(b * CIN + half * 8)) * (HH * WW)
                            + h * WW + w;
        const bool rok0 = (h > 0), rok2 = (h < HH - 1);
        const bool cok0 = (w > 0), cok2 = (w < WW - 1);

#pragma unroll
        for (int i = 0; i < 9; ++i) {
            float v[8];
#pragma unroll
            for (int j = 0; j < 8; ++j) {
                const int qq = i * 8 + j;          // 0..71 (compile-time)
                const int cl = qq / 9;             // 0..7
                const int rr = qq % 9;
                const int kh = rr / 3, kw = rr % 3;
                const bool rv = (kh == 1) || (kh == 0 ? rok0 : rok2);
                const bool cv = (kw == 1) || (kw == 0 ? cok0 : cok2);
                const int off = cl * (HH * WW) + (kh - 1) * WW + (kw - 1);
                v[j] = (rv && cv) ? xb[off] : 0.0f;
            }
            uint4 pk;
            pk.x = pk2(v[0], v[1]); pk.y = pk2(v[2], v[3]);
            pk.z = pk2(v[4], v[5]); pk.w = pk2(v[6], v[7]);
            *(uint4*)&Abf[b][half * 72 + i * 8] = pk;
        }
        // zero-pad p in [144,160): 32 rows x 32 B = 64 lanes x 16 B
        uint4 z; z.x = z.y = z.z = z.w = 0u;
        *(uint4*)&Abf[l >> 1][PP + (l & 1) * 8] = z;
    }
    __syncthreads();

    // ---------------- compute: 32x32 = [2x2] 16x16 MFMA tiles ----------------
    const int lm = l & 15;        // n-col within 16-tile / m-row for A
    const int q  = l >> 4;        // 0..3

    const float* wloc = weights + (size_t)(h * WW + w) * (COUT * PP);
    const float* wl0  = wloc + (size_t)lm * PP;          // o = lm      (nt=0)
    const float* wl1  = wloc + (size_t)(lm + 16) * PP;   // o = lm + 16 (nt=1)

    v4f acc00 = {0,0,0,0}, acc01 = {0,0,0,0};
    v4f acc10 = {0,0,0,0}, acc11 = {0,0,0,0};

#pragma unroll
    for (int kc = 0; kc < 5; ++kc) {
        const int kb = kc * 32 + q * 8;   // start p of this lane's 8-elem frag

        v8s a0 = *(const v8s*)&Abf[lm     ][kb];
        v8s a1 = *(const v8s*)&Abf[lm + 16][kb];

        v8s b0 = {0,0,0,0,0,0,0,0};
        v8s b1 = {0,0,0,0,0,0,0,0};
        if (kb < PP) {   // kb multiple of 8; kb<144 => full 8 valid
            float4 f0 = *(const float4*)(wl0 + kb);
            float4 f1 = *(const float4*)(wl0 + kb + 4);
            float4 g0 = *(const float4*)(wl1 + kb);
            float4 g1 = *(const float4*)(wl1 + kb + 4);
            U16 ub, ug;
            ub.u.x = pk2(f0.x, f0.y); ub.u.y = pk2(f0.z, f0.w);
            ub.u.z = pk2(f1.x, f1.y); ub.u.w = pk2(f1.z, f1.w);
            ug.u.x = pk2(g0.x, g0.y); ug.u.y = pk2(g0.z, g0.w);
            ug.u.z = pk2(g1.x, g1.y); ug.u.w = pk2(g1.z, g1.w);
            b0 = ub.s; b1 = ug.s;
        }

        acc00 = __builtin_amdgcn_mfma_f32_16x16x32_bf16(a0, b0, acc00, 0, 0, 0);
        acc01 = __builtin_amdgcn_mfma_f32_16x16x32_bf16(a0, b1, acc01, 0, 0, 0);
        acc10 = __builtin_amdgcn_mfma_f32_16x16x32_bf16(a1, b0, acc10, 0, 0, 0);
        acc11 = __builtin_amdgcn_mfma_f32_16x16x32_bf16(a1, b1, acc11, 0, 0, 0);
    }

    // ---------------- epilogue: bias + scattered stores ----------------
    const float bia0 = bias[(size_t)(h * WW + w) * COUT + lm];
    const float bia1 = bias[(size_t)(h * WW + w) * COUT + 16 + lm];
    float* obase = out + h * WW + w;

#pragma unroll
    for (int mt = 0; mt < 2; ++mt) {
#pragma unroll
        for (int j = 0; j < 4; ++j) {
            const int bidx = mt * 16 + q * 4 + j;       // batch row (C/D row)
            const v4f& r0 = mt ? acc10 : acc00;
            const v4f& r1 = mt ? acc11 : acc01;
            obase[(size_t)(bidx * COUT + lm)      * (HH * WW)] = r0[j] + bia0;
            obase[(size_t)(bidx * COUT + 16 + lm) * (HH * WW)] = r1[j] + bia1;
        }
    }
}

extern "C" void kernel_launch(void* const* d_in, const int* in_sizes, int n_in,
                              void* d_out, int out_size, void* d_ws, size_t ws_size,
                              hipStream_t stream) {
    const float* x       = (const float*)d_in[0];
    const float* weights = (const float*)d_in[1];
    const float* bias    = (const float*)d_in[2];
    float* out           = (float*)d_out;
    (void)in_sizes; (void)n_in; (void)out_size; (void)d_ws; (void)ws_size;

    dim3 grid(HH * WW);   // 4096 blocks, one per output location
    dim3 block(64);       // one wave
    hipLaunchKernelGGL(xonv_kernel, grid, block, 0, stream, x, weights, bias, out);
}

// Round 2
// 130.498 us; speedup vs baseline: 1.4628x; 1.4628x over previous
//
#include <hip/hip_runtime.h>

// Xonv2D: per-location conv. B=32, CIN=16, H=W=64, COUT=32, K=3, pad=1.
// out[b,o,h,w] = sum_{c,kh,kw} x[b,c,h+kh-1,w+kw-1] * W[h,w,o,c,kh,kw] + bias[h,w,o]
//
// R2: address-coalescing rewrite. Block = 512 thr (8 waves) = 8 consecutive w
// at one h; one wave per location runs the verified 32x32x144 bf16-MFMA GEMM.
//  - x staged cooperatively into LDS rows [b][c][r][10] (bf16) via aligned
//    float4 window loads; A-frags gathered with ds_read_u16 (LDS scatter is
//    cheap; global scatter was the R1 bottleneck).
//  - weights: unchanged verified per-lane contiguous float4 reads (the
//    compulsory 75.5 MB stream, L3-resident).
//  - output: accumulators transposed through LDS (aliased over the x buffer)
//    then stored as coalesced w-runs (kills the 2048 line-touch/loc scatter).
// XCD swizzle: h%8 = XCD, so all 8 w-groups of a row share an XCD L2.

#define BB      32
#define CIN     16
#define HH      64
#define WW      64
#define COUT    32
#define PP      144    // CIN*3*3
#define WT      8      // w-tile per block
#define NCOL    10     // staged cols per (b,c,r): w0-1 .. w0+8
#define BSTRIDE 498    // halfwords per b in xl: 480 data + 16 zero-pad + 2 spare
#define ZOFF    480    // zero region start (hw) for p >= 144

typedef float v4f __attribute__((ext_vector_type(4)));
typedef short v8s __attribute__((ext_vector_type(8)));

__device__ __forceinline__ unsigned short f2bf(float f) {
    unsigned int u = __builtin_bit_cast(unsigned int, f);
    u += 0x7fffu + ((u >> 16) & 1u);          // RNE
    return (unsigned short)(u >> 16);
}
__device__ __forceinline__ unsigned int pk2(float a, float b) {
    return (unsigned int)f2bf(a) | ((unsigned int)f2bf(b) << 16);
}

union U16 { uint4 u; v8s s; };

__global__ __launch_bounds__(512, 4) void xonv_kernel(
    const float* __restrict__ x,
    const float* __restrict__ weights,
    const float* __restrict__ bias,
    float* __restrict__ out)
{
    const int t  = threadIdx.x;
    const int bi = blockIdx.x;                 // 0..511

    // XCD swizzle: xcd = h%8; all 8 w-groups of an h-row on one XCD.
    const int xcd  = bi & 7;
    const int rest = bi >> 3;                  // 0..63
    const int wg   = rest & 7;                 // w-group 0..7
    const int h    = (rest >> 3) * 8 + xcd;    // 0..63
    const int w0   = wg * WT;

    __shared__ alignas(16) unsigned char smraw[36864];
    unsigned short* xl = (unsigned short*)smraw;   // [32][BSTRIDE] bf16
    float*          ol = (float*)smraw;            // epilogue: [1024][9] f32

    // ---- zero-pad region (p in [144,160)): hw [b*498+480, +496) ----
    if (t < 256) {
        const int b = t >> 3, k = t & 7;
        ((unsigned int*)smraw)[b * 249 + 240 + k] = 0u;
    }

    // ---------------- stage x rows into LDS (bf16) ----------------
    // seg = b*48 + c*3 + r ; 1536 segs, 3 per thread.
    const bool wg0    = (wg == 0);
    const int  wstart = wg0 ? 0 : (w0 - 4);    // aligned float4 window base
#pragma unroll
    for (int s = 0; s < 3; ++s) {
        const int seg = t + s * 512;
        const int b   = seg / 48;
        const int cr  = seg % 48;              // c*3 + r
        const int c   = cr / 3;
        const int r   = cr % 3;
        const int row = h + r - 1;
        const bool rvalid = ((unsigned)row < HH);

        float win[16];
        if (rvalid) {
            const float* src = x + ((size_t)(b * CIN + c)) * (HH * WW) + row * WW;
#pragma unroll
            for (int k = 0; k < 4; ++k) {
                const int col4 = wstart + 4 * k;
                float4 f = {0.f, 0.f, 0.f, 0.f};
                if (col4 <= WW - 4) f = *(const float4*)(src + col4);
                win[4 * k + 0] = f.x; win[4 * k + 1] = f.y;
                win[4 * k + 2] = f.z; win[4 * k + 3] = f.w;
            }
        } else {
#pragma unroll
            for (int k = 0; k < 16; ++k) win[k] = 0.f;
        }

        // cols j = 0..9 map to real col w0-1+j
        float vals[NCOL];
        if (wg0) {
            vals[0] = 0.f;                      // real col -1
#pragma unroll
            for (int j = 1; j < NCOL; ++j) vals[j] = win[j - 1];
        } else {
#pragma unroll
            for (int j = 0; j < NCOL; ++j) vals[j] = win[j + 3];
        }

        unsigned int* d32 = (unsigned int*)(xl + b * BSTRIDE + cr * NCOL);
#pragma unroll
        for (int k = 0; k < 5; ++k)
            d32[k] = pk2(vals[2 * k], vals[2 * k + 1]);
    }
    __syncthreads();

    // ---------------- compute: one wave per location ----------------
    const int l  = t & 63;
    const int wv = t >> 6;                      // wave = location 0..7
    const int lm = l & 15;
    const int q  = l >> 4;
    const int w  = w0 + wv;

    const float* wlocp = weights + (size_t)(h * WW + w) * (COUT * PP);
    const float* wl0   = wlocp + (size_t)lm * PP;          // o = lm
    const float* wl1   = wlocp + (size_t)(lm + 16) * PP;   // o = lm+16

    const unsigned short* xr0 = xl + lm * BSTRIDE;         // b = lm
    const unsigned short* xr1 = xl + (lm + 16) * BSTRIDE;  // b = lm+16

    v4f acc00 = {0,0,0,0}, acc01 = {0,0,0,0};
    v4f acc10 = {0,0,0,0}, acc11 = {0,0,0,0};

#pragma unroll
    for (int kc = 0; kc < 5; ++kc) {
        const int p0 = kc * 32 + q * 8;

        v8s a0, a1;
#pragma unroll
        for (int j = 0; j < 8; ++j) {
            const int pj  = p0 + j;
            const int c   = (pj * 57) >> 9;       // pj/9, exact for pj<144
            const int rem = pj - c * 9;
            const int rr  = (rem * 11) >> 5;      // rem/3
            const int kw  = rem - rr * 3;
            int hw = (c * 3 + rr) * NCOL + wv + kw;
            hw = (pj < PP) ? hw : (ZOFF + (pj - PP));   // zeros for p>=144
            a0[j] = (short)xr0[hw];
            a1[j] = (short)xr1[hw];
        }

        v8s b0 = {0,0,0,0,0,0,0,0};
        v8s b1 = {0,0,0,0,0,0,0,0};
        if (p0 < PP) {
            float4 f0 = *(const float4*)(wl0 + p0);
            float4 f1 = *(const float4*)(wl0 + p0 + 4);
            float4 g0 = *(const float4*)(wl1 + p0);
            float4 g1 = *(const float4*)(wl1 + p0 + 4);
            U16 ub, ug;
            ub.u.x = pk2(f0.x, f0.y); ub.u.y = pk2(f0.z, f0.w);
            ub.u.z = pk2(f1.x, f1.y); ub.u.w = pk2(f1.z, f1.w);
            ug.u.x = pk2(g0.x, g0.y); ug.u.y = pk2(g0.z, g0.w);
            ug.u.z = pk2(g1.x, g1.y); ug.u.w = pk2(g1.z, g1.w);
            b0 = ub.s; b1 = ug.s;
        }

        acc00 = __builtin_amdgcn_mfma_f32_16x16x32_bf16(a0, b0, acc00, 0, 0, 0);
        acc01 = __builtin_amdgcn_mfma_f32_16x16x32_bf16(a0, b1, acc01, 0, 0, 0);
        acc10 = __builtin_amdgcn_mfma_f32_16x16x32_bf16(a1, b0, acc10, 0, 0, 0);
        acc11 = __builtin_amdgcn_mfma_f32_16x16x32_bf16(a1, b1, acc11, 0, 0, 0);
    }

    // ---------------- epilogue: bias + LDS transpose + coalesced stores ----
    const float bia0 = bias[(size_t)(h * WW + w) * COUT + lm];
    const float bia1 = bias[(size_t)(h * WW + w) * COUT + 16 + lm];

    __syncthreads();   // all xl reads done; smraw reused as ol[1024][9]

#pragma unroll
    for (int mt = 0; mt < 2; ++mt) {
#pragma unroll
        for (int j = 0; j < 4; ++j) {
            const int b = mt * 16 + q * 4 + j;      // C/D row = batch
            const v4f& r0 = mt ? acc10 : acc00;
            const v4f& r1 = mt ? acc11 : acc01;
            ol[(b * COUT + lm) * 9 + wv]        = r0[j] + bia0;
            ol[(b * COUT + 16 + lm) * 9 + wv]   = r1[j] + bia1;
        }
    }
    __syncthreads();

    // coalesced store: 16 lanes-per-seg... thread t: seg = t>>3 (0..63), wj = t&7
    {
        const int seg = t >> 3;
        const int wj  = t & 7;
        float* ob = out + (size_t)h * WW + w0 + wj;
#pragma unroll
        for (int i = 0; i < 16; ++i) {
            const int bo = i * 64 + seg;            // (b*32+o) 0..1023
            ob[(size_t)bo * (HH * WW)] = ol[bo * 9 + wj];
        }
    }
}

extern "C" void kernel_launch(void* const* d_in, const int* in_sizes, int n_in,
                              void* d_out, int out_size, void* d_ws, size_t ws_size,
                              hipStream_t stream) {
    const float* x       = (const float*)d_in[0];
    const float* weights = (const float*)d_in[1];
    const float* bias    = (const float*)d_in[2];
    float* out           = (float*)d_out;
    (void)in_sizes; (void)n_in; (void)out_size; (void)d_ws; (void)ws_size;

    dim3 grid(512);    // 64 h x 8 w-groups, XCD-swizzled
    dim3 block(512);   // 8 waves = 8 locations
    hipLaunchKernelGGL(xonv_kernel, grid, block, 0, stream, x, weights, bias, out);
}

// Round 3
// 129.237 us; speedup vs baseline: 1.4771x; 1.0098x over previous
//
#include <hip/hip_runtime.h>

// Xonv2D: per-location conv. B=32, CIN=16, H=W=64, COUT=32, K=3, pad=1.
// out[b,o,h,w] = sum_{c,kh,kw} x[b,c,h+kh-1,w+kw-1] * W[h,w,o,c,kh,kw] + bias[h,w,o]
//
// R3: 32x32x16 MFMA (K=16 | 144 -> 9 exact chunks, no tail), one acc per
// location covering all (b,o). Coalesced x staging (4 lanes/row, 16-slot
// bf16 windows, ds_write2), conflict-free A-gather (row stride 770 hw ->
// 385 dw == 1 mod 32), depth-1 register prefetch on the weight stream.

#define CIN     16
#define HH      64
#define WW      64
#define COUT    32
#define PP      144      // CIN*3*3
#define WT      8        // w-locations per block
#define RSTRIDE 770      // hw per b: 48 rows * 16 slots + 2 pad (dw stride 385 == 1 mod 32)

typedef float v4f  __attribute__((ext_vector_type(4)));
typedef float v16f __attribute__((ext_vector_type(16)));
typedef short v8s  __attribute__((ext_vector_type(8)));

__device__ __forceinline__ unsigned short f2bf(float f) {
    unsigned int u = __builtin_bit_cast(unsigned int, f);
    u += 0x7fffu + ((u >> 16) & 1u);          // RNE
    return (unsigned short)(u >> 16);
}
__device__ __forceinline__ unsigned int pk2(float a, float b) {
    return (unsigned int)f2bf(a) | ((unsigned int)f2bf(b) << 16);
}

__global__ __launch_bounds__(512, 4) void xonv_kernel(
    const float* __restrict__ x,
    const float* __restrict__ weights,
    const float* __restrict__ bias,
    float* __restrict__ out)
{
    const int t  = threadIdx.x;
    const int bi = blockIdx.x;                 // 0..511

    // XCD swizzle: all 8 w-groups of an h-row share an XCD.
    const int xcd  = bi & 7;
    const int rest = bi >> 3;
    const int wg   = rest & 7;
    const int h    = (rest >> 3) * 8 + xcd;
    const int w0   = wg * WT;
    const int wstart = w0 - 4;                 // aligned 16-float window base

    __shared__ alignas(16) unsigned char smraw[49280];
    unsigned short* xl = (unsigned short*)smraw;   // [32][RSTRIDE] bf16 windows
    float*          ol = (float*)smraw;            // epilogue: [1024][9] f32

    // ---------------- stage x: 1536 rows x 16-float windows ----------------
    // row id = b*48 + (c*3 + r); 4 lanes per row (sub = which float4).
    {
        const int rid0 = t >> 2;               // 0..127
        const int sub  = t & 3;
        int b  = rid0 / 48;
        int cr = rid0 % 48;
        const int col4  = wstart + sub * 4;
        const bool colok = (col4 >= 0) && (col4 <= WW - 4);
#pragma unroll
        for (int pass = 0; pass < 12; ++pass) {
            const int c   = cr / 3;
            const int r   = cr - c * 3;
            const int row = h + r - 1;
            float4 f = {0.f, 0.f, 0.f, 0.f};
            if (colok && (unsigned)row < HH) {
                f = *(const float4*)(x + ((size_t)(b * CIN + c)) * (HH * WW)
                                       + row * WW + col4);
            }
            unsigned int* d = (unsigned int*)(xl + b * RSTRIDE + cr * 16 + sub * 4);
            d[0] = pk2(f.x, f.y);
            d[1] = pk2(f.z, f.w);
            b += 2; cr += 32; if (cr >= 48) { cr -= 48; ++b; }   // +128 rows
        }
    }
    __syncthreads();

    // ---------------- compute: one wave per location, 32x32x16 MFMA --------
    const int l  = t & 63;
    const int wv = t >> 6;                     // location in w-tile, 0..7
    const int w  = w0 + wv;
    const int o  = l & 31;                     // also A row b = l&31
    const int kh = l >> 5;                     // k-half
    const int ph = kh * 8;

    const float* wp = weights + (size_t)(h * WW + w) * (COUT * PP)
                              + (size_t)o * PP + ph;
    const int xbase = (l & 31) * RSTRIDE + wv + 3;

    v16f acc;
#pragma unroll
    for (int i = 0; i < 16; ++i) acc[i] = 0.f;

    int dq = ph >> 2;    // p0/3 for p0 = ph (0->0, 8->2)
    int mq = ph >> 2;    // p0%3           (0->0, 8->2)

    v4f c0 = *(const v4f*)(wp);
    v4f c1 = *(const v4f*)(wp + 4);

#pragma unroll
    for (int kc = 0; kc < 9; ++kc) {
        v4f n0, n1;
        if (kc < 8) {
            n0 = *(const v4f*)(wp + (kc + 1) * 16);
            n1 = *(const v4f*)(wp + (kc + 1) * 16 + 4);
        }

        // gather A-frag: p = kc*16 + ph + j ; slot = (p/3)*16 + p%3 + wv + 3
        v8s a;
        const int base = xbase + dq * 16 + mq;
#pragma unroll
        for (int j = 0; j < 8; ++j) {
            const int e  = mq + j;             // <= 9
            const int tt = (e * 11) >> 5;      // e/3
            a[j] = (short)xl[base + j + 13 * tt];
        }

        // pack B-frag from prefetched weights
        union { unsigned int u[4]; v8s s; } ub;
        ub.u[0] = pk2(c0.x, c0.y); ub.u[1] = pk2(c0.z, c0.w);
        ub.u[2] = pk2(c1.x, c1.y); ub.u[3] = pk2(c1.z, c1.w);

        acc = __builtin_amdgcn_mfma_f32_32x32x16_bf16(a, ub.s, acc, 0, 0, 0);

        c0 = n0; c1 = n1;
        mq += 1; dq += 5; if (mq == 3) { mq = 0; dq += 1; }   // p0 += 16
    }

    // ---------------- epilogue: bias + LDS transpose + coalesced stores ----
    const float bia = bias[(size_t)(h * WW + w) * COUT + o];

    __syncthreads();   // xl reads done; reuse smraw as ol[1024][9]

#pragma unroll
    for (int r = 0; r < 16; ++r) {
        const int brow = (r & 3) + 8 * (r >> 2) + 4 * kh;   // batch index
        ol[(brow * COUT + o) * 9 + wv] = acc[r] + bia;
    }
    __syncthreads();

    // coalesced store: thread t -> seg = t>>3 (0..63), wj = t&7
    {
        const int seg = t >> 3;
        const int wj  = t & 7;
        float* ob = out + (size_t)h * WW + w0 + wj;
#pragma unroll
        for (int i = 0; i < 16; ++i) {
            const int bo = i * 64 + seg;                    // b*32 + o
            ob[(size_t)bo * (HH * WW)] = ol[bo * 9 + wj];
        }
    }
}

extern "C" void kernel_launch(void* const* d_in, const int* in_sizes, int n_in,
                              void* d_out, int out_size, void* d_ws, size_t ws_size,
                              hipStream_t stream) {
    const float* x       = (const float*)d_in[0];
    const float* weights = (const float*)d_in[1];
    const float* bias    = (const float*)d_in[2];
    float* out           = (float*)d_out;
    (void)in_sizes; (void)n_in; (void)out_size; (void)d_ws; (void)ws_size;

    dim3 grid(512);    // 64 h x 8 w-groups, XCD-swizzled
    dim3 block(512);   // 8 waves = 8 locations
    hipLaunchKernelGGL(xonv_kernel, grid, block, 0, stream, x, weights, bias, out);
}

// Round 4
// 125.859 us; speedup vs baseline: 1.5167x; 1.0268x over previous
//
#include <hip/hip_runtime.h>

// Xonv2D: per-location conv. B=32, CIN=16, H=W=64, COUT=32, K=3, pad=1.
// out[b,o,h,w] = sum_{c,kh,kw} x[b,c,h+kh-1,w+kw-1] * W[h,w,o,c,kh,kw] + bias[h,w,o]
//
// R4: HBM-bound regime (harness ws-poison flushes L3 every iter -> weights
// stream from HBM each call). Block = 16 waves = 16 consecutive w at one h:
//  - full-line 64-B output stores (16 w per block) -> no write-allocate RMW
//  - x windows staged once per block (amp 4.5x), same-row blocks share XCD L2
//  - weight loads issued before staging + depth-2 prefetch: 32 KB/CU in
//    flight >> 9.2 KB Little's-law requirement at 6.3 TB/s
//  - A-gather offsets are compile-time tables (cndmask on lane half);
//    LDS b-stride 481 dw == 1 mod 32 -> conflict-free ds_read_u16 gather.

#define CIN  16
#define HW_  4096            // H*W
#define PP   144             // CIN*3*3
#define RST  20              // hw per (b, c*3+r) row: slot = col - w0 + 2
#define BST  962             // hw per b: 48*20 + 2 pad (dw 481 == 1 mod 32)

typedef float v4f  __attribute__((ext_vector_type(4)));
typedef float v16f __attribute__((ext_vector_type(16)));
typedef short v8s  __attribute__((ext_vector_type(8)));

__device__ __forceinline__ unsigned short f2bf(float f) {
    unsigned int u = __builtin_bit_cast(unsigned int, f);
    u += 0x7fffu + ((u >> 16) & 1u);          // RNE
    return (unsigned short)(u >> 16);
}
__device__ __forceinline__ unsigned int pk2(float a, float b) {
    return (unsigned int)f2bf(a) | ((unsigned int)f2bf(b) << 16);
}
__device__ __forceinline__ constexpr int offp(int p) {
    // p = c*9 + r*3 + kw  ->  LDS hw offset (row part + kw + 1)
    const int c = p / 9, rem = p % 9, r = rem / 3, kw = rem % 3;
    return (c * 3 + r) * RST + kw + 1;
}

__global__ __launch_bounds__(1024, 4) void xonv_kernel(
    const float* __restrict__ x,
    const float* __restrict__ wt,
    const float* __restrict__ bias,
    float* __restrict__ out)
{
    const int t  = threadIdx.x;
    const int bi = blockIdx.x;                 // 0..255
    // XCD swizzle: bi&7 = h&7 -> all 4 w-groups of a row on one XCD.
    const int h  = ((bi >> 5) << 3) + (bi & 7);
    const int wg = (bi >> 3) & 3;
    const int w0 = wg << 4;

    __shared__ unsigned short xs[32 * BST];    // 61,568 B
    float* ol = (float*)xs;                    // epilogue alias (34,816 B)

    const int l  = t & 63;
    const int wv = t >> 6;                     // wave = location 0..15
    const int w  = w0 + wv;
    const int o  = l & 31;                     // out-channel col / batch row
    const int kh = l >> 5;                     // k-half (0/1)

    // ---- issue weight prefetch EARLY (independent of LDS) ----
    const float* wp = wt + (size_t)(h * 64 + w) * (32 * PP)
                         + (size_t)o * PP + kh * 8;
    v4f c00 = *(const v4f*)(wp);
    v4f c01 = *(const v4f*)(wp + 4);
    v4f c10 = *(const v4f*)(wp + 16);
    v4f c11 = *(const v4f*)(wp + 20);
    const float bia = bias[(size_t)(h * 64 + w) * 32 + o];

    // ---------------- stage x windows: 1536 rows x 6 float4 ----------------
    // job j: rid = j/6 (row = b*48 + c*3 + r), sub = j%6; window col w0-4+sub*4
    const int wstart = w0 - 4;
#pragma unroll
    for (int i = 0; i < 9; ++i) {
        const int j   = t + i * 1024;
        const int rid = (int)(((unsigned)j * 43691u) >> 18);   // j/6
        const int sub = j - rid * 6;
        const int b   = (rid * 683) >> 15;                     // rid/48
        const int cr  = rid - b * 48;
        const int c   = (cr * 43) >> 7;                        // cr/3
        const int r   = cr - c * 3;
        const int row = h + r - 1;
        const int col4 = wstart + sub * 4;
        float4 f = {0.f, 0.f, 0.f, 0.f};
        if ((unsigned)row < 64u && (unsigned)col4 <= 60u)
            f = *(const float4*)(x + ((size_t)(b * CIN + c)) * HW_
                                   + row * 64 + col4);
        unsigned short* dst = xs + b * BST + cr * RST;
        if (sub == 0) {
            ((unsigned int*)dst)[0] = pk2(f.z, f.w);           // slots 0,1
        } else if (sub == 5) {
            ((unsigned int*)dst)[9] = pk2(f.x, f.y);           // slots 18,19
        } else {
            unsigned int* d = (unsigned int*)(dst + sub * 4 - 2);
            d[0] = pk2(f.x, f.y);                              // slots 4s-2..
            d[1] = pk2(f.z, f.w);
        }
    }
    __syncthreads();

    // ---------------- compute: one wave per location, 9 x 32x32x16 ---------
    const int gb = o * BST + wv;               // per-lane gather base (hw)

    v16f acc;
#pragma unroll
    for (int i = 0; i < 16; ++i) acc[i] = 0.f;

#pragma unroll
    for (int kc = 0; kc < 9; ++kc) {
        v4f n0, n1;
        if (kc < 7) {
            n0 = *(const v4f*)(wp + (kc + 2) * 16);
            n1 = *(const v4f*)(wp + (kc + 2) * 16 + 4);
        } else {
            n0 = c10; n1 = c11;
        }

        v8s a;
#pragma unroll
        for (int j = 0; j < 8; ++j) {
            const int C0 = offp(kc * 16 + j);        // compile-time
            const int C1 = offp(kc * 16 + 8 + j);    // compile-time
            a[j] = (short)xs[gb + (kh ? C1 : C0)];
        }

        union { unsigned int u[4]; v8s s; } ub;
        ub.u[0] = pk2(c00.x, c00.y); ub.u[1] = pk2(c00.z, c00.w);
        ub.u[2] = pk2(c01.x, c01.y); ub.u[3] = pk2(c01.z, c01.w);

        acc = __builtin_amdgcn_mfma_f32_32x32x16_bf16(a, ub.s, acc, 0, 0, 0);

        c00 = c10; c01 = c11; c10 = n0; c11 = n1;
    }

    __syncthreads();   // all xs gathers done; reuse LDS as ol[512][17]

    // ---------------- epilogue: two b-halves, full-line stores -------------
#pragma unroll
    for (int half = 0; half < 2; ++half) {
#pragma unroll
        for (int rr = 0; rr < 8; ++rr) {
            const int r     = half * 8 + rr;
            const int browl = (r & 3) + 8 * ((r >> 2) & 1) + 4 * kh;  // 0..15
            ol[(browl * 32 + o) * 17 + wv] = acc[r] + bia;
        }
        __syncthreads();
#pragma unroll
        for (int i2 = 0; i2 < 2; ++i2) {
            const int flat = t + i2 * 1024;
            const int bol  = flat >> 2;            // 0..511 : browl*32+o
            const int q4   = flat & 3;
            const int base = bol * 17 + q4 * 4;
            float4 v;
            v.x = ol[base + 0]; v.y = ol[base + 1];
            v.z = ol[base + 2]; v.w = ol[base + 3];
            const int bg = half * 16 + (bol >> 5);         // batch
            const int og = bol & 31;                       // out-channel
            *(float4*)(out + ((size_t)(bg * 32 + og)) * HW_
                           + h * 64 + w0 + q4 * 4) = v;
        }
        __syncthreads();
    }
}

extern "C" void kernel_launch(void* const* d_in, const int* in_sizes, int n_in,
                              void* d_out, int out_size, void* d_ws, size_t ws_size,
                              hipStream_t stream) {
    const float* x       = (const float*)d_in[0];
    const float* weights = (const float*)d_in[1];
    const float* bias    = (const float*)d_in[2];
    float* out           = (float*)d_out;
    (void)in_sizes; (void)n_in; (void)out_size; (void)d_ws; (void)ws_size;

    dim3 grid(256);     // 64 h x 4 w-groups, XCD-swizzled
    dim3 block(1024);   // 16 waves = 16 w-locations
    hipLaunchKernelGGL(xonv_kernel, grid, block, 0, stream, x, weights, bias, out);
}